// Round 6
// baseline (183.113 us; speedup 1.0000x reference)
//
#include <hip/hip_runtime.h>
#include <math.h>

#define IC_   2048
#define NC_   16
#define OD_   16
#define ID_   8
#define B_    128
#define NCH_  128            // i-chunks
#define IPC_  (IC_/NCH_)     // 16 i per chunk
#define LOG2E_ 1.4426950408889634f

typedef _Float16 h2 __attribute__((ext_vector_type(2)));
typedef _Float16 h4 __attribute__((ext_vector_type(4)));
typedef _Float16 h8 __attribute__((ext_vector_type(8)));
typedef float    f4 __attribute__((ext_vector_type(4)));

// ---------------- fp32 -> fp16 flat conversion (8 elems/thread) ----------------
__global__ __launch_bounds__(256)
void cvt16(const float* __restrict__ in, _Float16* __restrict__ out, int n8) {
  for (int idx = blockIdx.x * 256 + threadIdx.x; idx < n8; idx += gridDim.x * 256) {
    const float4 a = ((const float4*)in)[2 * idx];
    const float4 b = ((const float4*)in)[2 * idx + 1];
    h8 h;
    h[0] = (_Float16)a.x; h[1] = (_Float16)a.y; h[2] = (_Float16)a.z; h[3] = (_Float16)a.w;
    h[4] = (_Float16)b.x; h[5] = (_Float16)b.y; h[6] = (_Float16)b.z; h[7] = (_Float16)b.w;
    ((h8*)out)[idx] = h;
  }
}

// ---------------- MFMA routing pass v2: 4 c's per wave ----------------
// Grid: (128 i-chunks, 8 b-tiles). Block: 4 waves; wave wid owns c in [wid*4, wid*4+4),
// ALL 16 i's of the chunk. MFMA 16x16x16f16 per c: A=W[i,c] (m=o, k=d, lanes>=32 zero),
// B=x (k=d, n=b). D: col=lane&15=b, row=(lane>>4)*4+reg=o.
// Softmax: per-wave partial Z exchanged via 512B double-buffered LDS (1 barrier/iter).
// Waves own disjoint c's -> no final reduce; direct fp16-packed global stores.
template<bool UNIFORM>
__global__ __launch_bounds__(256)
void caps_mfma2(const _Float16* __restrict__ xh, const _Float16* __restrict__ Wh,
                const float* __restrict__ vs, unsigned int* __restrict__ s_part) {
  const int chunk = blockIdx.x;
  const int bt    = blockIdx.y;
  const int tid   = threadIdx.x;
  const int wid   = tid >> 6;
  const int lane  = tid & 63;
  const int m     = lane & 15;        // A-row(o) / B-col(b) / D-col(b)
  const int g4    = lane >> 4;        // 0..3
  const bool lo   = lane < 32;
  const int i0    = chunk * IPC_;
  const int c0    = wid * 4;

  __shared__ float Zbuf[2][4][16];

  f4 sreg[4];
#pragma unroll
  for (int cc = 0; cc < 4; ++cc) sreg[cc] = (f4)0.f;

  f4 vv[4];
  if (!UNIFORM) {
    const float* vb = vs + (size_t)(bt * 16 + m) * 256 + g4 * 4;
#pragma unroll
    for (int cc = 0; cc < 4; ++cc) vv[cc] = *(const f4*)(vb + (c0 + cc) * 16);
  }

  if (UNIFORM) {
    // pack 2 i's into K=16: k-blocks {0,1} -> i_even, {2,3} -> i_odd (sum over i wanted)
    const int ieo = g4 >> 1;
    const int gk2 = g4 & 1;
    for (int t = 0; t < IPC_ / 2; ++t) {
      const int i = i0 + 2 * t + ieo;
      const h4 xb = *(const h4*)(xh + ((size_t)(bt * 16 + m) * IC_ + i) * ID_ + gk2 * 4);
      const _Float16* wbase = Wh + ((size_t)i * 256 + m) * ID_ + gk2 * 4;
#pragma unroll
      for (int cc = 0; cc < 4; ++cc) {
        const h4 a = *(const h4*)(wbase + (c0 + cc) * (16 * ID_));
        sreg[cc] = __builtin_amdgcn_mfma_f32_16x16x16f16(a, xb, sreg[cc], 0, 0, 0);
      }
    }
  } else {
    const int gk = g4 & 1;
    for (int t = 0; t < IPC_; ++t) {
      const int i = i0 + t;
      h4 xb{};
      if (lo) xb = *(const h4*)(xh + ((size_t)(bt * 16 + m) * IC_ + i) * ID_ + gk * 4);
      const _Float16* wbase = Wh + ((size_t)i * 256 + m) * ID_ + gk * 4;

      f4 u[4];
#pragma unroll
      for (int cc = 0; cc < 4; ++cc) {
        h4 a{};
        if (lo) a = *(const h4*)(wbase + (c0 + cc) * (16 * ID_));
        u[cc] = __builtin_amdgcn_mfma_f32_16x16x16f16(a, xb, (f4)0.f, 0, 0, 0);
      }

      float e[4];
      float Zw = 0.f;
#pragma unroll
      for (int cc = 0; cc < 4; ++cc) {
        float p = u[cc][0] * vv[cc][0];
        p = fmaf(u[cc][1], vv[cc][1], p);
        p = fmaf(u[cc][2], vv[cc][2], p);
        p = fmaf(u[cc][3], vv[cc][3], p);
        p += __shfl_xor(p, 16);
        p += __shfl_xor(p, 32);
        e[cc] = __builtin_amdgcn_exp2f(p);   // vs pre-scaled by log2e; |logit| tiny
        Zw += e[cc];
      }

      const int par = t & 1;
      if (g4 == 0) Zbuf[par][wid][m] = Zw;
      __syncthreads();
      const float Z = Zbuf[par][0][m] + Zbuf[par][1][m] + Zbuf[par][2][m] + Zbuf[par][3][m];
      const float r = __builtin_amdgcn_rcpf(Z);

#pragma unroll
      for (int cc = 0; cc < 4; ++cc) {
        const float w = e[cc] * r;
        sreg[cc][0] = fmaf(w, u[cc][0], sreg[cc][0]);
        sreg[cc][1] = fmaf(w, u[cc][1], sreg[cc][1]);
        sreg[cc][2] = fmaf(w, u[cc][2], sreg[cc][2]);
        sreg[cc][3] = fmaf(w, u[cc][3], sreg[cc][3]);
      }
    }
  }

  // fp16-pack and store: wave owns c0..c0+3 (disjoint), dword f layout matches reduce2:
  // f = (c*64 + lane)*4 + r  ->  dword (c*64+lane)*2 + (r>>1), half r&1.
  unsigned int* dst = s_part + (size_t)(chunk * 8 + bt) * 2048;
#pragma unroll
  for (int cc = 0; cc < 4; ++cc) {
    h2 p0; p0[0] = (_Float16)sreg[cc][0]; p0[1] = (_Float16)sreg[cc][1];
    h2 p1; p1[0] = (_Float16)sreg[cc][2]; p1[1] = (_Float16)sreg[cc][3];
    uint2 dw;
    dw.x = __builtin_bit_cast(unsigned int, p0);
    dw.y = __builtin_bit_cast(unsigned int, p1);
    *(uint2*)(dst + (c0 + cc) * 128 + lane * 2) = dw;
  }
}

// ---------------- reduce over NCH_ chunks + squash (MFMA-path layout) ----------------
// mode 0: vraw=v1, vs_next=v1*log2e (scale=1/16); mode 1: vs_next=(v1raw+v2)*log2e;
// mode 2: out=v3.
__global__ __launch_bounds__(256)
void caps_reduce2(const unsigned int* __restrict__ sp, float* __restrict__ vraw,
                  float* __restrict__ vs_next, float* __restrict__ out,
                  const float* __restrict__ v_prev_raw, float scale, int mode) {
  const int b = blockIdx.x;
  const int t = threadIdx.x;          // t = co = c*16 + o
  const int c = t >> 4, o = t & 15;
  const int r = o & 3, g = o >> 2;
  const int l = g * 16 + (b & 15);
  const int f = (c * 64 + l) * 4 + r;
  const int dwidx = f >> 1, hi = f & 1;
  const int bt = b >> 4;

  float s = 0.f;
  for (int ch = 0; ch < NCH_; ++ch) {
    const unsigned int dw = sp[(size_t)(ch * 8 + bt) * 2048 + dwidx];
    const h2 hv = __builtin_bit_cast(h2, dw);
    s += (float)(hi ? hv[1] : hv[0]);
  }
  s *= scale;

  float sq = s * s;
  sq += __shfl_xor(sq, 1);
  sq += __shfl_xor(sq, 2);
  sq += __shfl_xor(sq, 4);
  sq += __shfl_xor(sq, 8);
  const float fq = sq / ((1.f + sq) * sqrtf(sq + 1e-8f));
  const float v = s * fq;

  if (mode == 0) {
    vraw[b * 256 + t]    = v;
    vs_next[b * 256 + t] = v * LOG2E_;
  } else if (mode == 1) {
    vs_next[b * 256 + t] = (v + v_prev_raw[b * 256 + t]) * LOG2E_;
  } else {
    out[b * 256 + t] = v;
  }
}

// ================= fp32 fallback (round-3 proven) =================
__device__ __forceinline__ float4 ld4(const float* p) { return *(const float4*)p; }
__device__ __forceinline__ float dot8f(float4 a0, float4 a1, float4 b0, float4 b1) {
  float s = a0.x * b0.x;
  s = fmaf(a0.y, b0.y, s); s = fmaf(a0.z, b0.z, s); s = fmaf(a0.w, b0.w, s);
  s = fmaf(a1.x, b1.x, s); s = fmaf(a1.y, b1.y, s); s = fmaf(a1.z, b1.z, s);
  s = fmaf(a1.w, b1.w, s);
  return s;
}
template<int CTRL>
__device__ __forceinline__ float dpp_add(float x) {
  const int xi = __builtin_bit_cast(int, x);
  const int yi = __builtin_amdgcn_update_dpp(xi, xi, CTRL, 0xF, 0xF, false);
  return x + __builtin_bit_cast(float, yi);
}
__device__ __forceinline__ float row16_sum(float x) {
  x = dpp_add<0x0B1>(x); x = dpp_add<0x04E>(x);
  x = dpp_add<0x141>(x); x = dpp_add<0x140>(x);
  return x;
}
template<bool UNIFORM, int CH>
__global__ __launch_bounds__(256)
void caps_pass_f32(const float* __restrict__ x, const float* __restrict__ W,
                   const float* __restrict__ vs, float* __restrict__ s_part) {
  constexpr int ICPB  = IC_ / CH;
  constexpr int TITER = ICPB / 4;
  const int bg = blockIdx.x, ch = blockIdx.y, tid = threadIdx.x;
  const int wid = tid >> 6, lane = tid & 63;
  float4 vr[4];
  if (!UNIFORM) {
#pragma unroll
    for (int bb = 0; bb < 4; ++bb) {
      const float* vp = vs + (size_t)(bg * 4 + bb) * 256 + lane;
      vr[bb] = make_float4(vp[0], vp[64], vp[128], vp[192]);
    }
  }
  float4 acc[4];
#pragma unroll
  for (int bb = 0; bb < 4; ++bb) acc[bb] = make_float4(0.f, 0.f, 0.f, 0.f);
  for (int t = 0; t < TITER; ++t) {
    const int i = ch * ICPB + t * 4 + wid;
    const float* wr = W + (size_t)i * 2048 + lane * 8;
    const float4 wa0 = ld4(wr);        const float4 wa1 = ld4(wr + 4);
    const float4 wb0 = ld4(wr + 512);  const float4 wb1 = ld4(wr + 516);
    const float4 wc0 = ld4(wr + 1024); const float4 wc1 = ld4(wr + 1028);
    const float4 wd0 = ld4(wr + 1536); const float4 wd1 = ld4(wr + 1540);
#pragma unroll
    for (int bb = 0; bb < 4; ++bb) {
      const float* xp = x + ((size_t)(bg * 4 + bb) * IC_ + i) * ID_;
      const float4 x0 = ld4(xp), x1 = ld4(xp + 4);
      const float u0 = dot8f(wa0, wa1, x0, x1);
      const float u1 = dot8f(wb0, wb1, x0, x1);
      const float u2 = dot8f(wc0, wc1, x0, x1);
      const float u3 = dot8f(wd0, wd1, x0, x1);
      if (UNIFORM) {
        acc[bb].x += u0; acc[bb].y += u1; acc[bb].z += u2; acc[bb].w += u3;
      } else {
        const float d0 = row16_sum(u0 * vr[bb].x);
        const float d1 = row16_sum(u1 * vr[bb].y);
        const float d2 = row16_sum(u2 * vr[bb].z);
        const float d3 = row16_sum(u3 * vr[bb].w);
        const float e0 = __builtin_amdgcn_exp2f(d0);
        const float e1 = __builtin_amdgcn_exp2f(d1);
        const float e2 = __builtin_amdgcn_exp2f(d2);
        const float e3 = __builtin_amdgcn_exp2f(d3);
        float Z = (e0 + e1) + (e2 + e3);
        Z += __shfl_xor(Z, 16); Z += __shfl_xor(Z, 32);
        const float rr = __builtin_amdgcn_rcpf(Z);
        acc[bb].x = fmaf(e0 * rr, u0, acc[bb].x);
        acc[bb].y = fmaf(e1 * rr, u1, acc[bb].y);
        acc[bb].z = fmaf(e2 * rr, u2, acc[bb].z);
        acc[bb].w = fmaf(e3 * rr, u3, acc[bb].w);
      }
    }
  }
  __shared__ float red[4][4 * 256];
#pragma unroll
  for (int bb = 0; bb < 4; ++bb) {
    red[wid][bb * 256 + lane]       = acc[bb].x;
    red[wid][bb * 256 + lane + 64]  = acc[bb].y;
    red[wid][bb * 256 + lane + 128] = acc[bb].z;
    red[wid][bb * 256 + lane + 192] = acc[bb].w;
  }
  __syncthreads();
#pragma unroll
  for (int bb = 0; bb < 4; ++bb) {
    const int idx = bb * 256 + tid;
    const float s = red[0][idx] + red[1][idx] + red[2][idx] + red[3][idx];
    s_part[((size_t)(bg * 4 + bb) * CH + ch) * 256 + tid] = s;
  }
}
__global__ __launch_bounds__(256)
void caps_reduce(const float* __restrict__ s_part, float* __restrict__ vraw,
                 float* __restrict__ vs_next, float* __restrict__ out,
                 const float* __restrict__ v_prev_raw, float scale, int mode, int nch) {
  const int b = blockIdx.x, t = threadIdx.x;
  float s = 0.f;
  for (int ch = 0; ch < nch; ++ch)
    s += s_part[((size_t)b * nch + ch) * 256 + t];
  s *= scale;
  float sq = s * s;
  sq += __shfl_xor(sq, 1); sq += __shfl_xor(sq, 2);
  sq += __shfl_xor(sq, 4); sq += __shfl_xor(sq, 8);
  const float f = sq / ((1.f + sq) * sqrtf(sq + 1e-8f));
  const float v = s * f;
  if (mode == 0) { vraw[b*256+t] = v; vs_next[b*256+t] = v * LOG2E_; }
  else if (mode == 1) { vs_next[b*256+t] = (v + v_prev_raw[b*256+t]) * LOG2E_; }
  else { out[b*256+t] = v; }
}

extern "C" void kernel_launch(void* const* d_in, const int* in_sizes, int n_in,
                              void* d_out, int out_size, void* d_ws, size_t ws_size,
                              hipStream_t stream) {
  (void)in_sizes; (void)n_in; (void)out_size;

  const float* x = (const float*)d_in[0];
  const float* W = (const float*)d_in[1];
  float* out = (float*)d_out;

  const size_t nW = (size_t)IC_ * NC_ * OD_ * ID_;   // 4 Mi
  const size_t nX = (size_t)B_ * IC_ * ID_;          // 2 Mi
  const size_t sp_bytes  = (size_t)NCH_ * 8 * 2048 * 4;    // 8 MB
  const size_t v_bytes   = (size_t)B_ * 256 * 4;           // 128 KB
  const size_t need_mfma = sp_bytes + 2 * v_bytes + nW * 2 + nX * 2;  // ~20.3 MB

  const dim3 blk(256), gridR(B_);

  if (ws_size >= need_mfma) {
    unsigned int* spdw = (unsigned int*)d_ws;
    float* v1raw = (float*)((char*)d_ws + sp_bytes);
    float* vsb   = v1raw + (size_t)B_ * 256;
    _Float16* Wh = (_Float16*)(vsb + (size_t)B_ * 256);
    _Float16* xh = Wh + nW;

    cvt16<<<2048, blk, 0, stream>>>(W, Wh, (int)(nW / 8));
    cvt16<<<1024, blk, 0, stream>>>(x, xh, (int)(nX / 8));

    const dim3 gridP(NCH_, 8);
    caps_mfma2<true ><<<gridP, blk, 0, stream>>>(xh, Wh, nullptr, spdw);
    caps_reduce2<<<gridR, blk, 0, stream>>>(spdw, v1raw, vsb, nullptr, nullptr, 1.f/16.f, 0);
    caps_mfma2<false><<<gridP, blk, 0, stream>>>(xh, Wh, vsb, spdw);
    caps_reduce2<<<gridR, blk, 0, stream>>>(spdw, nullptr, vsb, nullptr, v1raw, 1.f, 1);
    caps_mfma2<false><<<gridP, blk, 0, stream>>>(xh, Wh, vsb, spdw);
    caps_reduce2<<<gridR, blk, 0, stream>>>(spdw, nullptr, nullptr, out, nullptr, 1.f, 2);
  } else {
    constexpr int CH = 32;
    float* s_part = (float*)d_ws;
    float* v1raw  = s_part + (size_t)B_ * CH * 256;
    float* vsb    = v1raw + (size_t)B_ * 256;
    const dim3 gridP(B_ / 4, CH);
    caps_pass_f32<true , CH><<<gridP, blk, 0, stream>>>(x, W, nullptr, s_part);
    caps_reduce<<<gridR, blk, 0, stream>>>(s_part, v1raw, vsb, nullptr, nullptr, 1.f/16.f, 0, CH);
    caps_pass_f32<false, CH><<<gridP, blk, 0, stream>>>(x, W, vsb, s_part);
    caps_reduce<<<gridR, blk, 0, stream>>>(s_part, nullptr, vsb, nullptr, v1raw, 1.f, 1, CH);
    caps_pass_f32<false, CH><<<gridP, blk, 0, stream>>>(x, W, vsb, s_part);
    caps_reduce<<<gridR, blk, 0, stream>>>(s_part, nullptr, nullptr, out, nullptr, 1.f, 2, CH);
  }
}

// Round 7
// 125.846 us; speedup vs baseline: 1.4551x; 1.4551x over previous
//
#include <hip/hip_runtime.h>
#include <math.h>

#define IC_   2048
#define NC_   16
#define OD_   16
#define ID_   8
#define B_    128
#define LOG2E_ 1.4426950408889634f

// pass1 geometry
#define P1_BB   8
#define P1_CH   64
#define P1_ICPB (IC_/P1_CH)     // 32 i per block
// pass2/3 geometry
#define P2_NCH  16
#define P2_IPB  (IC_/P2_NCH)    // 128 i per block
#define P2_IPW  (P2_IPB/4)      // 32 i per wave

typedef _Float16 h2 __attribute__((ext_vector_type(2)));
typedef _Float16 h8 __attribute__((ext_vector_type(8)));

// lane (l,k) -> original co row: c = l&15, o = (l>>4)+4k
__device__ __forceinline__ int origco(int lane, int k) {
  return ((lane & 15) << 4) + (lane >> 4) + 4 * k;
}

template<int CTRL>
__device__ __forceinline__ float dpp_add(float x) {
  const int xi = __builtin_bit_cast(int, x);
  const int yi = __builtin_amdgcn_update_dpp(xi, xi, CTRL, 0xF, 0xF, false);
  return x + __builtin_bit_cast(float, yi);
}
// butterfly sum across each 16-lane row (result in all lanes of the row)
__device__ __forceinline__ float row16_sum(float x) {
  x = dpp_add<0x0B1>(x);  // quad_perm xor1
  x = dpp_add<0x04E>(x);  // quad_perm xor2
  x = dpp_add<0x141>(x);  // row_half_mirror xor4
  x = dpp_add<0x140>(x);  // row_mirror xor8
  return x;
}

__device__ __forceinline__ float dot8h(h8 w, h8 x) {
  const h2 w0 = __builtin_shufflevector(w, w, 0, 1), x0 = __builtin_shufflevector(x, x, 0, 1);
  const h2 w1 = __builtin_shufflevector(w, w, 2, 3), x1 = __builtin_shufflevector(x, x, 2, 3);
  const h2 w2 = __builtin_shufflevector(w, w, 4, 5), x2 = __builtin_shufflevector(x, x, 4, 5);
  const h2 w3 = __builtin_shufflevector(w, w, 6, 7), x3 = __builtin_shufflevector(x, x, 6, 7);
  float s = __builtin_amdgcn_fdot2(w0, x0, 0.f, false);
  s = __builtin_amdgcn_fdot2(w1, x1, s, false);
  s = __builtin_amdgcn_fdot2(w2, x2, s, false);
  s = __builtin_amdgcn_fdot2(w3, x3, s, false);
  return s;
}

// ---------- fp32 -> fp16 flat conversion (x), 8 elems/thread ----------
__global__ __launch_bounds__(256)
void cvt16(const float* __restrict__ in, _Float16* __restrict__ out, int n8) {
  for (int idx = blockIdx.x * 256 + threadIdx.x; idx < n8; idx += gridDim.x * 256) {
    const float4 a = ((const float4*)in)[2 * idx];
    const float4 b = ((const float4*)in)[2 * idx + 1];
    h8 h;
    h[0] = (_Float16)a.x; h[1] = (_Float16)a.y; h[2] = (_Float16)a.z; h[3] = (_Float16)a.w;
    h[4] = (_Float16)b.x; h[5] = (_Float16)b.y; h[6] = (_Float16)b.z; h[7] = (_Float16)b.w;
    ((h8*)out)[idx] = h;
  }
}

// ---------- W fp32->fp16 with row permutation ----------
// Wp[i][rp] = W[i][ro] where, for ro = c*16+o:  rp = c + ((o&3)<<4) + ((o>>2)<<6).
// Then pass1's coalesced read at row (lane + 64k) yields co = origco(lane,k).
__global__ __launch_bounds__(256)
void cvtW(const float* __restrict__ in, _Float16* __restrict__ out) {
  const int idx = blockIdx.x * 256 + threadIdx.x;   // i*256 + ro,  total 2048*256
  const int ro  = idx & 255;
  const int i   = idx >> 8;
  const int rp  = (ro >> 4) + ((ro & 3) << 4) + (((ro >> 2) & 3) << 6);
  const float4 a = ((const float4*)in)[2 * idx];
  const float4 b = ((const float4*)in)[2 * idx + 1];
  h8 h;
  h[0] = (_Float16)a.x; h[1] = (_Float16)a.y; h[2] = (_Float16)a.z; h[3] = (_Float16)a.w;
  h[4] = (_Float16)b.x; h[5] = (_Float16)b.y; h[6] = (_Float16)b.z; h[7] = (_Float16)b.w;
  *(h8*)(out + ((size_t)i * 256 + rp) * ID_) = h;
}

// ---------- pass 1: compute u_hat (store fp16-packed) + uniform-weight s1 partials ----------
// Grid (B/BB=16, CH=64). Wave handles 8 i's; lane l computes u for co=origco(l,k), k=0..3,
// via coalesced reads of permuted Wp rows (l+64k). W regs reused across 8 batch elements.
__global__ __launch_bounds__(256)
void caps_pass1(const _Float16* __restrict__ xh, const _Float16* __restrict__ Wp,
                unsigned int* __restrict__ u_hat, float* __restrict__ s_part) {
  const int bg = blockIdx.x;
  const int ch = blockIdx.y;
  const int tid = threadIdx.x, wid = tid >> 6, lane = tid & 63;

  float acc[P1_BB][4];
#pragma unroll
  for (int bb = 0; bb < P1_BB; ++bb)
#pragma unroll
    for (int k = 0; k < 4; ++k) acc[bb][k] = 0.f;

  for (int t = 0; t < P1_ICPB / 4; ++t) {
    const int i = ch * P1_ICPB + t * 4 + wid;
    const _Float16* wr = Wp + (size_t)i * 2048 + lane * ID_;
    const h8 w0 = *(const h8*)(wr);
    const h8 w1 = *(const h8*)(wr + 512);
    const h8 w2 = *(const h8*)(wr + 1024);
    const h8 w3 = *(const h8*)(wr + 1536);

#pragma unroll
    for (int bb = 0; bb < P1_BB; ++bb) {
      const int b = bg * P1_BB + bb;
      const h8 xv = *(const h8*)(xh + ((size_t)b * IC_ + i) * ID_);
      const float u0 = dot8h(w0, xv);
      const float u1 = dot8h(w1, xv);
      const float u2 = dot8h(w2, xv);
      const float u3 = dot8h(w3, xv);
      acc[bb][0] += u0; acc[bb][1] += u1; acc[bb][2] += u2; acc[bb][3] += u3;
      h2 p0; p0[0] = (_Float16)u0; p0[1] = (_Float16)u1;   // RNE
      h2 p1; p1[0] = (_Float16)u2; p1[1] = (_Float16)u3;
      uint2 dw;
      dw.x = __builtin_bit_cast(unsigned int, p0);
      dw.y = __builtin_bit_cast(unsigned int, p1);
      *(uint2*)(u_hat + ((size_t)b * IC_ + i) * 128 + lane * 2) = dw;
    }
  }

  __shared__ float red[4][P1_BB * 256];
#pragma unroll
  for (int bb = 0; bb < P1_BB; ++bb)
#pragma unroll
    for (int k = 0; k < 4; ++k)
      red[wid][bb * 256 + origco(lane, k)] = acc[bb][k];
  __syncthreads();
#pragma unroll
  for (int bb = 0; bb < P1_BB; ++bb) {
    const int idx = bb * 256 + tid;
    const float s = red[0][idx] + red[1][idx] + red[2][idx] + red[3][idx];
    s_part[((size_t)(bg * P1_BB + bb) * P1_CH + ch) * 256 + tid] = s;
  }
}

// ---------- pass 2/3: streaming softmax-weighted accumulation over u_hat ----------
// Grid (B=128, 16). Block = 4 waves, same b; wave handles 32 i's.
// Lane l holds u for c=l&15, o=(l>>4)+4k. logit: 4 FMA + xor16 + xor32 (full in all lanes);
// 1 exp/lane; Z = row16 DPP sum over the 16 c's; acc in regs; 4-wave LDS reduce at end.
__global__ __launch_bounds__(256)
void caps_wpass(const unsigned int* __restrict__ u_hat, const float* __restrict__ vs,
                float* __restrict__ s_part) {
  const int b   = blockIdx.x;
  const int ich = blockIdx.y;
  const int tid = threadIdx.x, wid = tid >> 6, lane = tid & 63;

  const float vv0 = vs[b * 256 + origco(lane, 0)];
  const float vv1 = vs[b * 256 + origco(lane, 1)];
  const float vv2 = vs[b * 256 + origco(lane, 2)];
  const float vv3 = vs[b * 256 + origco(lane, 3)];

  float a0 = 0.f, a1 = 0.f, a2 = 0.f, a3 = 0.f;
  const unsigned int* up =
      u_hat + ((size_t)b * IC_ + ich * P2_IPB + wid * P2_IPW) * 128 + lane * 2;

#pragma unroll 4
  for (int t = 0; t < P2_IPW; ++t) {
    const uint2 dw = *(const uint2*)(up + (size_t)t * 128);
    const h2 ha = __builtin_bit_cast(h2, dw.x);
    const h2 hb = __builtin_bit_cast(h2, dw.y);
    const float u0 = (float)ha[0], u1 = (float)ha[1];
    const float u2 = (float)hb[0], u3 = (float)hb[1];

    float p = u0 * vv0;
    p = fmaf(u1, vv1, p);
    p = fmaf(u2, vv2, p);
    p = fmaf(u3, vv3, p);
    p += __shfl_xor(p, 16);
    p += __shfl_xor(p, 32);                  // logit[c] * log2e, in all lanes
    const float e = __builtin_amdgcn_exp2f(p);
    const float Z = row16_sum(e);            // sum over the 16 c's
    const float w = e * __builtin_amdgcn_rcpf(Z);
    a0 = fmaf(w, u0, a0);
    a1 = fmaf(w, u1, a1);
    a2 = fmaf(w, u2, a2);
    a3 = fmaf(w, u3, a3);
  }

  __shared__ float red[4][256];
  red[wid][origco(lane, 0)] = a0;
  red[wid][origco(lane, 1)] = a1;
  red[wid][origco(lane, 2)] = a2;
  red[wid][origco(lane, 3)] = a3;
  __syncthreads();
  const float s = red[0][tid] + red[1][tid] + red[2][tid] + red[3][tid];
  s_part[((size_t)b * P2_NCH + ich) * 256 + tid] = s;
}

// ---------- reduce over nch chunks + squash ----------
// mode 0: vraw=v1, vs_next=v1*log2e (scale=1/16); mode 1: vs_next=(v1raw+v2)*log2e;
// mode 2: out=v3.
__global__ __launch_bounds__(256)
void caps_reduce(const float* __restrict__ s_part, float* __restrict__ vraw,
                 float* __restrict__ vs_next, float* __restrict__ out,
                 const float* __restrict__ v_prev_raw, float scale, int mode, int nch) {
  const int b = blockIdx.x, t = threadIdx.x;
  float s = 0.f;
  for (int ch = 0; ch < nch; ++ch)
    s += s_part[((size_t)b * nch + ch) * 256 + t];
  s *= scale;
  float sq = s * s;
  sq += __shfl_xor(sq, 1); sq += __shfl_xor(sq, 2);
  sq += __shfl_xor(sq, 4); sq += __shfl_xor(sq, 8);
  const float f = sq / ((1.f + sq) * sqrtf(sq + 1e-8f));
  const float v = s * f;
  if (mode == 0) { vraw[b*256+t] = v; vs_next[b*256+t] = v * LOG2E_; }
  else if (mode == 1) { vs_next[b*256+t] = (v + v_prev_raw[b*256+t]) * LOG2E_; }
  else { out[b*256+t] = v; }
}

// ================= fp32 fallback (round-3 proven) =================
__device__ __forceinline__ float4 ld4(const float* p) { return *(const float4*)p; }
__device__ __forceinline__ float dot8f(float4 a0, float4 a1, float4 b0, float4 b1) {
  float s = a0.x * b0.x;
  s = fmaf(a0.y, b0.y, s); s = fmaf(a0.z, b0.z, s); s = fmaf(a0.w, b0.w, s);
  s = fmaf(a1.x, b1.x, s); s = fmaf(a1.y, b1.y, s); s = fmaf(a1.z, b1.z, s);
  s = fmaf(a1.w, b1.w, s);
  return s;
}
template<bool UNIFORM, int CH>
__global__ __launch_bounds__(256)
void caps_pass_f32(const float* __restrict__ x, const float* __restrict__ W,
                   const float* __restrict__ vs, float* __restrict__ s_part) {
  constexpr int ICPB  = IC_ / CH;
  constexpr int TITER = ICPB / 4;
  const int bg = blockIdx.x, ch = blockIdx.y, tid = threadIdx.x;
  const int wid = tid >> 6, lane = tid & 63;
  float4 vr[4];
  if (!UNIFORM) {
#pragma unroll
    for (int bb = 0; bb < 4; ++bb) {
      const float* vp = vs + (size_t)(bg * 4 + bb) * 256 + lane;
      vr[bb] = make_float4(vp[0], vp[64], vp[128], vp[192]);
    }
  }
  float4 acc[4];
#pragma unroll
  for (int bb = 0; bb < 4; ++bb) acc[bb] = make_float4(0.f, 0.f, 0.f, 0.f);
  for (int t = 0; t < TITER; ++t) {
    const int i = ch * ICPB + t * 4 + wid;
    const float* wr = W + (size_t)i * 2048 + lane * 8;
    const float4 wa0 = ld4(wr);        const float4 wa1 = ld4(wr + 4);
    const float4 wb0 = ld4(wr + 512);  const float4 wb1 = ld4(wr + 516);
    const float4 wc0 = ld4(wr + 1024); const float4 wc1 = ld4(wr + 1028);
    const float4 wd0 = ld4(wr + 1536); const float4 wd1 = ld4(wr + 1540);
#pragma unroll
    for (int bb = 0; bb < 4; ++bb) {
      const float* xp = x + ((size_t)(bg * 4 + bb) * IC_ + i) * ID_;
      const float4 x0 = ld4(xp), x1 = ld4(xp + 4);
      const float u0 = dot8f(wa0, wa1, x0, x1);
      const float u1 = dot8f(wb0, wb1, x0, x1);
      const float u2 = dot8f(wc0, wc1, x0, x1);
      const float u3 = dot8f(wd0, wd1, x0, x1);
      if (UNIFORM) {
        acc[bb].x += u0; acc[bb].y += u1; acc[bb].z += u2; acc[bb].w += u3;
      } else {
        const float d0 = row16_sum(u0 * vr[bb].x);
        const float d1 = row16_sum(u1 * vr[bb].y);
        const float d2 = row16_sum(u2 * vr[bb].z);
        const float d3 = row16_sum(u3 * vr[bb].w);
        const float e0 = __builtin_amdgcn_exp2f(d0);
        const float e1 = __builtin_amdgcn_exp2f(d1);
        const float e2 = __builtin_amdgcn_exp2f(d2);
        const float e3 = __builtin_amdgcn_exp2f(d3);
        float Z = (e0 + e1) + (e2 + e3);
        Z += __shfl_xor(Z, 16); Z += __shfl_xor(Z, 32);
        const float rr = __builtin_amdgcn_rcpf(Z);
        acc[bb].x = fmaf(e0 * rr, u0, acc[bb].x);
        acc[bb].y = fmaf(e1 * rr, u1, acc[bb].y);
        acc[bb].z = fmaf(e2 * rr, u2, acc[bb].z);
        acc[bb].w = fmaf(e3 * rr, u3, acc[bb].w);
      }
    }
  }
  __shared__ float red[4][4 * 256];
#pragma unroll
  for (int bb = 0; bb < 4; ++bb) {
    red[wid][bb * 256 + lane]       = acc[bb].x;
    red[wid][bb * 256 + lane + 64]  = acc[bb].y;
    red[wid][bb * 256 + lane + 128] = acc[bb].z;
    red[wid][bb * 256 + lane + 192] = acc[bb].w;
  }
  __syncthreads();
#pragma unroll
  for (int bb = 0; bb < 4; ++bb) {
    const int idx = bb * 256 + tid;
    const float s = red[0][idx] + red[1][idx] + red[2][idx] + red[3][idx];
    s_part[((size_t)(bg * 4 + bb) * CH + ch) * 256 + tid] = s;
  }
}

extern "C" void kernel_launch(void* const* d_in, const int* in_sizes, int n_in,
                              void* d_out, int out_size, void* d_ws, size_t ws_size,
                              hipStream_t stream) {
  (void)in_sizes; (void)n_in; (void)out_size;

  const float* x = (const float*)d_in[0];
  const float* W = (const float*)d_in[1];
  float* out = (float*)d_out;

  const size_t u_dw  = (size_t)B_ * IC_ * 128;            // 32 Mi dwords = 128 MiB
  const size_t sp_f  = (size_t)B_ * P1_CH * 256;          // 8 MiB worth of f32
  const size_t v_f   = (size_t)B_ * 256;
  const size_t nW    = (size_t)IC_ * 256 * ID_;           // 4 Mi fp16
  const size_t nX    = (size_t)B_ * IC_ * ID_;            // 2 Mi fp16
  const size_t need  = u_dw * 4 + sp_f * 4 + 2 * v_f * 4 + (nW + nX) * 2;  // ~148 MiB

  const dim3 blk(256), gridR(B_);

  if (ws_size >= need) {
    unsigned int* u_hat = (unsigned int*)d_ws;
    float* s_part = (float*)(u_hat + u_dw);
    float* v1raw  = s_part + sp_f;
    float* vsb    = v1raw + v_f;
    _Float16* Wh  = (_Float16*)(vsb + v_f);
    _Float16* xh  = Wh + nW;

    cvtW <<<2048, blk, 0, stream>>>(W, Wh);
    cvt16<<<1024, blk, 0, stream>>>(x, xh, (int)(nX / 8));

    caps_pass1<<<dim3(B_ / P1_BB, P1_CH), blk, 0, stream>>>(xh, Wh, u_hat, s_part);
    caps_reduce<<<gridR, blk, 0, stream>>>(s_part, v1raw, vsb, nullptr, nullptr,
                                           1.f / 16.f, 0, P1_CH);
    caps_wpass<<<dim3(B_, P2_NCH), blk, 0, stream>>>(u_hat, vsb, s_part);
    caps_reduce<<<gridR, blk, 0, stream>>>(s_part, nullptr, vsb, nullptr, v1raw,
                                           1.f, 1, P2_NCH);
    caps_wpass<<<dim3(B_, P2_NCH), blk, 0, stream>>>(u_hat, vsb, s_part);
    caps_reduce<<<gridR, blk, 0, stream>>>(s_part, nullptr, nullptr, out, nullptr,
                                           1.f, 2, P2_NCH);
  } else {
    constexpr int CH = 32;
    float* s_part = (float*)d_ws;
    float* v1raw  = s_part + (size_t)B_ * CH * 256;
    float* vsb    = v1raw + (size_t)B_ * 256;
    const dim3 gridP(B_ / 4, CH);
    caps_pass_f32<true , CH><<<gridP, blk, 0, stream>>>(x, W, nullptr, s_part);
    caps_reduce<<<gridR, blk, 0, stream>>>(s_part, v1raw, vsb, nullptr, nullptr, 1.f/16.f, 0, CH);
    caps_pass_f32<false, CH><<<gridP, blk, 0, stream>>>(x, W, vsb, s_part);
    caps_reduce<<<gridR, blk, 0, stream>>>(s_part, nullptr, vsb, nullptr, v1raw, 1.f, 1, CH);
    caps_pass_f32<false, CH><<<gridP, blk, 0, stream>>>(x, W, vsb, s_part);
    caps_reduce<<<gridR, blk, 0, stream>>>(s_part, nullptr, nullptr, out, nullptr, 1.f, 2, CH);
  }
}